// Round 12
// baseline (242.615 us; speedup 1.0000x reference)
//
#include <hip/hip_runtime.h>

// ContextAttentionBlock fused kernel for gfx950.
// Per (b,h) row-strip (2048 strips of [128x128]): everything in LDS with
// bf16 MFMA (32x32x16), fp32 accum. Shortcut conv folded into the output
// projection (w_sc @ Wo1 precomputed).
//
// R12 structure: FULL 160KB LDS, 5 buffers of 32KB:
//   XB (x), FTB (ft row-major), FPB (fp row-major), FPT (fp^T), FGT (fg^T).
// ft has its own buffer -> B1/B2/B3 merge into ONE phase (all read XB only),
// and B3 is no longer serialized between D and C. 5 barriers/strip:
//   P1{fp,fg,ft} | P2{D} | P3{V-ep, C} | P4{H-ep} | P5{E, out}
// Rotation: FTB is dead after P3 -> next strip's x staged there; XB/FTB swap.
//
// Measured history: R6 unroll2 kills spills (370->242); R8 16-wave TLP
// (242->162); R9 native cvt neutral; R10 reg-caching re-spilled (guard);
// R11 lgkm-only barriers neutral. VGPR cap = 65536/blockDim (1024->64).
// One acc live at a time (V-ep consumes D-acc before C) -> ~59 live regs.

typedef __bf16 bf16x8 __attribute__((ext_vector_type(8)));
typedef __bf16 bf16x4 __attribute__((ext_vector_type(4)));
typedef float f32x16 __attribute__((ext_vector_type(16)));

// byte offset inside a [128][128] bf16 buffer (256 B rows).
// XOR of row bits into byte-offset bits 4..7 spreads 32-consecutive-row
// column accesses over 16 distinct 16B slots (R2: conflicts 13.1M -> 2.6M).
__device__ __forceinline__ int swz(int row, int cb) {
    return (row << 8) + (cb ^ ((row & 15) << 4));
}
__device__ __forceinline__ float sigm(float t) {
    return 1.0f / (1.0f + __expf(-t));
}
// lgkm-only barrier: LDS consistent block-wide; global prefetch loads
// (vmcnt) ride through to their register use.
__device__ __forceinline__ void bar() {
    asm volatile("s_waitcnt lgkmcnt(0)" ::: "memory");
    __builtin_amdgcn_s_barrier();
    asm volatile("" ::: "memory");
}

// ---------------- pre-pass 1: combined shortcut weight -----------------
__global__ void prep_combine(const float* __restrict__ w_sc,
                             const float* __restrict__ b_sc,
                             const float* __restrict__ w_out,
                             const float* __restrict__ b_out,
                             float* __restrict__ wsc2,
                             float* __restrict__ bout2) {
    int k = blockIdx.x;      // 0..127
    int n = threadIdx.x;     // 0..127
    float acc = 0.f;
    for (int c = 0; c < 128; ++c)
        acc += w_sc[k * 128 + c] * w_out[(128 + c) * 128 + n];
    wsc2[k * 128 + n] = acc;
    if (k == 0) {
        float b = b_out[n];
        for (int c = 0; c < 128; ++c)
            b += b_sc[c] * w_out[(128 + c) * 128 + n];
        bout2[n] = b;
    }
}

// ---------------- pre-pass 2: pack weights into MFMA B-frag order ------
__global__ void prep_pack(const float* __restrict__ wth,
                          const float* __restrict__ wph,
                          const float* __restrict__ wg,
                          const float* __restrict__ wout,
                          const float* __restrict__ wsc2,
                          __bf16* __restrict__ packs) {
    int m = blockIdx.x;
    const float* src;
    int rowoff = 0;
    if (m == 0) src = wth;
    else if (m == 1) src = wph;
    else if (m == 2) src = wg;
    else if (m == 3) { src = wout; rowoff = 0; }
    else if (m == 4) { src = wout; rowoff = 256; }
    else src = wsc2;
    __bf16* dst = packs + m * 16384;
    for (int i = threadIdx.x; i < 16384; i += blockDim.x) {
        int j = i & 7;
        int lane = (i >> 3) & 63;
        int kk = (i >> 9) & 7;
        int nt = i >> 12;
        int k = kk * 16 + ((lane >> 5) << 3) + j;
        int n = nt * 32 + (lane & 31);
        dst[i] = (__bf16)(src[(rowoff + k) * 128 + n]);
    }
}

// ---------------- main fused kernel ------------------------------------
#define FPBo 65536
#define FPTo 98304
#define FGTo 131072

__global__ __launch_bounds__(1024, 1)
void cab_main(const float* __restrict__ x,
              const float* __restrict__ b_theta,
              const float* __restrict__ b_phi,
              const float* __restrict__ b_g,
              const __bf16* __restrict__ packs,
              const float* __restrict__ bout2,
              float* __restrict__ out,
              int nstrips, int spb) {
    __shared__ __align__(16) char lds[163840];

    const int tid = threadIdx.x;
    const int l   = tid & 63;
    const int wv  = tid >> 6;          // 0..15
    const int ct  = wv & 3;            // tile col (0..3)
    const int rt  = wv >> 2;           // tile row (0..3)
    const int ln  = l & 31;
    const int lh  = l >> 5;
    const int colg = ct * 32 + ln;     // this wave's output column
    const int m0   = rt * 32;          // this wave's output row base

    const __bf16* pTH = packs;
    const __bf16* pPH = packs + 16384;
    const __bf16* pG  = packs + 2 * 16384;
    const __bf16* pO0 = packs + 3 * 16384;
    const __bf16* pO2 = packs + 4 * 16384;
    const __bf16* pS2 = packs + 5 * 16384;

    const float biasTH = b_theta[colg];
    const float biasPH = b_phi[colg];
    const float biasG  = b_g[colg];
    const float biasO  = bout2[colg];

    const int s0 = blockIdx.x * spb;
    if (s0 >= nstrips) return;
    const float4* x4 = (const float4*)x;

    // staging geometry (1024 thr): idx = q*1024+tid -> row = q*32 + (tid>>5),
    // byte col = (tid&31)*8. Chunk c covers q = {2c, 2c+1} (rows c*64..+63).
    const int srow = tid >> 5;          // 0..31
    const int scb  = (tid & 31) * 8;    // byte col

    float4 pf[2];

    // initial full stage of strip s0 into buffer 0 (XB for it=0)
    {
        long base = (long)s0 * 4096;
#pragma unroll
        for (int c = 0; c < 2; ++c) {
#pragma unroll
            for (int q = 0; q < 2; ++q) pf[q] = x4[base + (c * 2 + q) * 1024 + tid];
#pragma unroll
            for (int q = 0; q < 2; ++q) {
                int row = (c * 2 + q) * 32 + srow;
                bf16x4 v;
                v[0] = (__bf16)pf[q].x; v[1] = (__bf16)pf[q].y;
                v[2] = (__bf16)pf[q].z; v[3] = (__bf16)pf[q].w;
                *(bf16x4*)(lds + swz(row, scb)) = v;
            }
        }
    }
    bar();

    for (int it = 0; it < spb; ++it) {
        const int s = s0 + it;
        // XB and FTB swap each iteration (FTB is dead after P3 -> stage there)
        const int XBo  = (it & 1) ? 32768 : 0;
        const int FTBo = 32768 - XBo;
        f32x16 acc;

        // ===== P1: fp -> FPB(row)+FPT(^T); fg -> FGT(^T); ft -> FTB(row)
        // B1: f_phi
#pragma unroll
        for (int i = 0; i < 16; ++i) acc[i] = 0.f;
#pragma unroll 2
        for (int kk = 0; kk < 8; ++kk) {
            bf16x8 b = *(const bf16x8*)(pPH + (((ct * 8 + kk) * 64 + l) << 3));
            bf16x8 a = *(const bf16x8*)(lds + XBo + swz(m0 + ln, kk * 32 + lh * 16));
            acc = __builtin_amdgcn_mfma_f32_32x32x16_bf16(a, b, acc, 0, 0, 0);
        }
#pragma unroll
        for (int r = 0; r < 16; ++r) {
            int row = m0 + (r & 3) + ((r >> 2) << 3) + (lh << 2);
            *(__bf16*)(lds + FPBo + swz(row, colg * 2)) = (__bf16)(acc[r] + biasPH);
        }
#pragma unroll
        for (int q = 0; q < 4; ++q) {
            int w0 = m0 + (q << 3) + (lh << 2);
            bf16x4 v;
#pragma unroll
            for (int e = 0; e < 4; ++e) v[e] = (__bf16)(acc[q * 4 + e] + biasPH);
            *(bf16x4*)(lds + FPTo + swz(colg, w0 * 2)) = v;
        }

        // B2: f_g
#pragma unroll
        for (int i = 0; i < 16; ++i) acc[i] = 0.f;
#pragma unroll 2
        for (int kk = 0; kk < 8; ++kk) {
            bf16x8 b = *(const bf16x8*)(pG + (((ct * 8 + kk) * 64 + l) << 3));
            bf16x8 a = *(const bf16x8*)(lds + XBo + swz(m0 + ln, kk * 32 + lh * 16));
            acc = __builtin_amdgcn_mfma_f32_32x32x16_bf16(a, b, acc, 0, 0, 0);
        }
#pragma unroll
        for (int q = 0; q < 4; ++q) {
            int w0 = m0 + (q << 3) + (lh << 2);
            bf16x4 v;
#pragma unroll
            for (int e = 0; e < 4; ++e) v[e] = (__bf16)(acc[q * 4 + e] + biasG);
            *(bf16x4*)(lds + FGTo + swz(colg, w0 * 2)) = v;
        }

        // B3: f_theta -> FTB row-major
#pragma unroll
        for (int i = 0; i < 16; ++i) acc[i] = 0.f;
#pragma unroll 2
        for (int kk = 0; kk < 8; ++kk) {
            bf16x8 b = *(const bf16x8*)(pTH + (((ct * 8 + kk) * 64 + l) << 3));
            bf16x8 a = *(const bf16x8*)(lds + XBo + swz(m0 + ln, kk * 32 + lh * 16));
            acc = __builtin_amdgcn_mfma_f32_32x32x16_bf16(a, b, acc, 0, 0, 0);
        }
#pragma unroll
        for (int r = 0; r < 16; ++r) {
            int row = m0 + (r & 3) + ((r >> 2) << 3) + (lh << 2);
            *(__bf16*)(lds + FTBo + swz(row, colg * 2)) = (__bf16)(acc[r] + biasTH);
        }
        bar();   // (1) all P1 outputs ready

        // issue chunk0 of next strip's x (hidden under P2+P3)
        if (it + 1 < spb) {
            long base = (long)(s + 1) * 4096;
#pragma unroll
            for (int q = 0; q < 2; ++q) pf[q] = x4[base + q * 1024 + tid];
        }

        // ===== P2: D: vlog[j][i] = sum_w fp[w][j] fg[w][i]
#pragma unroll
        for (int i = 0; i < 16; ++i) acc[i] = 0.f;
#pragma unroll 2
        for (int kk = 0; kk < 8; ++kk) {
            bf16x8 b = *(const bf16x8*)(lds + FGTo + swz(colg, kk * 32 + lh * 16));
            bf16x8 a = *(const bf16x8*)(lds + FPTo + swz(m0 + ln, kk * 32 + lh * 16));
            acc = __builtin_amdgcn_mfma_f32_32x32x16_bf16(a, b, acc, 0, 0, 0);
        }
        bar();   // (2) all D reads of FPT/FGT done

        // ===== P3: V epilogue (consumes D-acc) then C (new acc)
        // V[i][j] = sigm(D[j][i]) * x[i][j] -> overwrite FGT
#pragma unroll
        for (int q = 0; q < 4; ++q) {
            int j0 = m0 + (q << 3) + (lh << 2);
            bf16x4 xv = *(const bf16x4*)(lds + XBo + swz(colg, j0 * 2));
            bf16x4 v;
#pragma unroll
            for (int e = 0; e < 4; ++e)
                v[e] = (__bf16)(sigm(acc[q * 4 + e]) * (float)xv[e]);
            *(bf16x4*)(lds + FGTo + swz(colg, j0 * 2)) = v;
        }

        // C: hlog[v][w] = sum_c ft[v][c] fp[w][c]  (A=FTB rows, B=FPB rows)
#pragma unroll
        for (int i = 0; i < 16; ++i) acc[i] = 0.f;
#pragma unroll 2
        for (int kk = 0; kk < 8; ++kk) {
            bf16x8 b = *(const bf16x8*)(lds + FPBo + swz(colg, kk * 32 + lh * 16));
            bf16x8 a = *(const bf16x8*)(lds + FTBo + swz(m0 + ln, kk * 32 + lh * 16));
            acc = __builtin_amdgcn_mfma_f32_32x32x16_bf16(a, b, acc, 0, 0, 0);
        }
        bar();   // (3) C reads of FPB/FTB done; FTB free for staging

        // write chunk0 of next x into FTB; issue chunk1 (hidden under P4/P5)
        if (it + 1 < spb) {
#pragma unroll
            for (int q = 0; q < 2; ++q) {
                int row = q * 32 + srow;     // rows 0..63
                bf16x4 v;
                v[0] = (__bf16)pf[q].x; v[1] = (__bf16)pf[q].y;
                v[2] = (__bf16)pf[q].z; v[3] = (__bf16)pf[q].w;
                *(bf16x4*)(lds + FTBo + swz(row, scb)) = v;
            }
            long base = (long)(s + 1) * 4096;
#pragma unroll
            for (int q = 0; q < 2; ++q) pf[q] = x4[base + (2 + q) * 1024 + tid];
        }

        // ===== P4: H epilogue: H[w][v] = sigm(C[v][w]) * x[w][v] -> FPB
#pragma unroll
        for (int q = 0; q < 4; ++q) {
            int v0 = m0 + (q << 3) + (lh << 2);
            bf16x4 xv = *(const bf16x4*)(lds + XBo + swz(colg, v0 * 2));
            bf16x4 v;
#pragma unroll
            for (int e = 0; e < 4; ++e)
                v[e] = (__bf16)(sigm(acc[q * 4 + e]) * (float)xv[e]);
            *(bf16x4*)(lds + FPBo + swz(colg, v0 * 2)) = v;
        }
        bar();   // (4) H ready (E reads FPB rows cross-wave)

        // ===== P5: E: out = H @ Wo0 + V @ Wo2 + xb @ Wsc2 + bout2
#pragma unroll
        for (int i = 0; i < 16; ++i) acc[i] = 0.f;
#pragma unroll 2
        for (int kk = 0; kk < 8; ++kk) {
            bf16x8 b = *(const bf16x8*)(pO0 + (((ct * 8 + kk) * 64 + l) << 3));
            bf16x8 a = *(const bf16x8*)(lds + FPBo + swz(m0 + ln, kk * 32 + lh * 16));
            acc = __builtin_amdgcn_mfma_f32_32x32x16_bf16(a, b, acc, 0, 0, 0);
        }
#pragma unroll 2
        for (int kk = 0; kk < 8; ++kk) {
            bf16x8 b = *(const bf16x8*)(pO2 + (((ct * 8 + kk) * 64 + l) << 3));
            bf16x8 a = *(const bf16x8*)(lds + FGTo + swz(m0 + ln, kk * 32 + lh * 16));
            acc = __builtin_amdgcn_mfma_f32_32x32x16_bf16(a, b, acc, 0, 0, 0);
        }
#pragma unroll 2
        for (int kk = 0; kk < 8; ++kk) {
            bf16x8 b = *(const bf16x8*)(pS2 + (((ct * 8 + kk) * 64 + l) << 3));
            bf16x8 a = *(const bf16x8*)(lds + XBo + swz(m0 + ln, kk * 32 + lh * 16));
            acc = __builtin_amdgcn_mfma_f32_32x32x16_bf16(a, b, acc, 0, 0, 0);
        }
        {
            long obase = (long)s * 16384;
#pragma unroll
            for (int r = 0; r < 16; ++r) {
                int row = m0 + (r & 3) + ((r >> 2) << 3) + (lh << 2);
                out[obase + row * 128 + colg] = acc[r] + biasO;
            }
        }

        // write chunk1 of next x into FTB (rows 64..127)
        if (it + 1 < spb) {
#pragma unroll
            for (int q = 0; q < 2; ++q) {
                int row = 64 + q * 32 + srow;
                bf16x4 v;
                v[0] = (__bf16)pf[q].x; v[1] = (__bf16)pf[q].y;
                v[2] = (__bf16)pf[q].z; v[3] = (__bf16)pf[q].w;
                *(bf16x4*)(lds + FTBo + swz(row, scb)) = v;
            }
        }
        bar();   // (5) E's XB reads + next-x staging done; swap XB/FTB
    }
}

extern "C" void kernel_launch(void* const* d_in, const int* in_sizes, int n_in,
                              void* d_out, int out_size, void* d_ws, size_t ws_size,
                              hipStream_t stream) {
    const float* x       = (const float*)d_in[0];
    const float* w_theta = (const float*)d_in[1];
    const float* b_theta = (const float*)d_in[2];
    const float* w_phi   = (const float*)d_in[3];
    const float* b_phi   = (const float*)d_in[4];
    const float* w_g     = (const float*)d_in[5];
    const float* b_g     = (const float*)d_in[6];
    const float* w_sc    = (const float*)d_in[7];
    const float* b_sc    = (const float*)d_in[8];
    const float* w_out   = (const float*)d_in[9];
    const float* b_out   = (const float*)d_in[10];
    float* out = (float*)d_out;

    float* wsc2 = (float*)d_ws;                                        // 128*128 f32
    __bf16* packs = (__bf16*)((char*)d_ws + 65536);                    // 6*16384 bf16
    float* bout2 = (float*)((char*)d_ws + 65536 + 6 * 16384 * 2);      // 128 f32

    int NS = in_sizes[0] / 16384;   // 2048 strips
    int spb = NS / 256;             // strips per block (8)
    if (spb < 1) spb = 1;
    int grid = (NS + spb - 1) / spb;

    prep_combine<<<128, 128, 0, stream>>>(w_sc, b_sc, w_out, b_out, wsc2, bout2);
    prep_pack<<<6, 256, 0, stream>>>(w_theta, w_phi, w_g, w_out, wsc2, packs);
    cab_main<<<grid, 1024, 0, stream>>>(x, b_theta, b_phi, b_g, packs, bout2, out, NS, spb);
}